// Round 5
// baseline (404.467 us; speedup 1.0000x reference)
//
#include <hip/hip_runtime.h>

#define TT 512
#define BB 256
#define NN 128
#define MW 16            // chains per workgroup
#define NWG (BB / MW)    // 16 workgroups
#define STH 144          // state row stride in halves (288 B, 16B-aligned)

typedef __attribute__((ext_vector_type(8))) short short8_t;
typedef __attribute__((ext_vector_type(4))) float f32x4;

__device__ __forceinline__ unsigned short f2bf(float f) {
  unsigned u = __float_as_uint(f);
  return (unsigned short)((u + 0x7FFF + ((u >> 16) & 1)) >> 16);  // RNE
}
__device__ __forceinline__ float bf2f(unsigned short h) {
  return __uint_as_float(((unsigned)h) << 16);
}
// storage position p <-> original j:  j = 32w+16u+c  <->  p = 32w+2c+u
__device__ __forceinline__ int orig_j(int p) {
  return 32 * (p >> 5) + 16 * (p & 1) + ((p >> 1) & 15);
}

// One workgroup = 16 chains. Per step: 16x128x128 GEMM via 8 MFMA/wave.
// State V[m][p] bf16 in LDS (double-buffered). E=exp(trans) bf16 in VGPRs
// (B-fragments, k-axis permuted to match state storage order). Per-chain
// power-of-2 rescale (exact integer bookkeeping, stale-by-1 normalizer).
__global__ __launch_bounds__(256, 1) void crf_fused(
    const float* __restrict__ emit, const int* __restrict__ target,
    const void* __restrict__ maskp, const float* __restrict__ trans,
    const float* __restrict__ strans, const float* __restrict__ etrans,
    float* __restrict__ ws, float* __restrict__ out) {
  __shared__ __align__(16) unsigned short sV[2][MW * STH];
  __shared__ __align__(16) int nrm[2][MW];
  __shared__ __align__(16) int sC[MW];
  __shared__ int slen[MW];
  __shared__ float sscore;
  __shared__ int smax;

  const int tid = threadIdx.x;
  const int w = tid >> 6;       // wave: owns j-tiles {2w, 2w+1}
  const int l = tid & 63;
  const int c = l & 15;         // MFMA col (D) / A-row (A)
  const int qd = l >> 4;        // quad
  const int bg = blockIdx.x * MW;

  if (tid < MW) slen[tid] = 0;
  if (tid == 0) { sscore = 0.f; smax = 0; }
  __syncthreads();

  // ---- mask dtype detect + lengths + gold score (16 threads/chain) ----
  const unsigned char* mk8 = (const unsigned char*)maskp;
  const int* mk32 = (const int*)maskp;
  const bool is_u8 = (mk8[1] != 0);
  {
    const int mi = tid & 15;
    const int b = bg + mi;
    const int t0 = (tid >> 4) * 32;
    int cnt = 0;
    float sc = 0.f;
    for (int s = 0; s < 32; ++s) {
      int t = t0 + s;
      int m = is_u8 ? (mk8[t * BB + b] != 0) : (mk32[t * BB + b] != 0);
      if (m) {
        cnt++;
        int tg = target[t * BB + b];
        float v = emit[((size_t)t * BB + b) * NN + tg];
        v += (t > 0) ? trans[target[(t - 1) * BB + b] * NN + tg] : strans[tg];
        int mn = (t + 1 < TT) ? (is_u8 ? (mk8[(t + 1) * BB + b] != 0)
                                       : (mk32[(t + 1) * BB + b] != 0))
                              : 0;
        if (!mn) v += etrans[tg];
        sc += v;
      }
    }
    atomicAdd(&slen[mi], cnt);
    atomicAdd(&sscore, sc);
  }

  // ---- E B-fragments: eB[kt][u][jj] = E_perm[kt*32+qd*8+jj][32w+16u+c] ----
  short8_t eB[4][2];
#pragma unroll
  for (int kt = 0; kt < 4; ++kt)
#pragma unroll
    for (int u = 0; u < 2; ++u)
#pragma unroll
      for (int jj = 0; jj < 8; ++jj) {
        int kp = kt * 32 + qd * 8 + jj;
        int i = orig_j(kp);
        int j = 32 * w + 16 * u + c;
        eB[kt][u][jj] = (short)f2bf(__expf(trans[i * NN + j]));
      }

  // ---- init V_0[m][p] = exp(strans[j] + emit[0][b][j]) ----
  {
    const int m = tid & 15;
    const int b = bg + m;
    const int pbase = (tid >> 4) * 8;
#pragma unroll
    for (int pp = 0; pp < 8; ++pp) {
      int p = pbase + pp;
      int j = orig_j(p);
      float v = __expf(strans[j] + emit[(size_t)b * NN + j]);
      sV[0][m * STH + p] = f2bf(v);
      if (p == 0)
        nrm[0][m] = ((int)((__float_as_uint(v) >> 23) & 0xFF)) - 120;  // exp+7
    }
  }
  __syncthreads();

  if (tid < MW) atomicMax(&smax, slen[tid]);
  if (tid == 0) atomicAdd(&ws[1], sscore);
  __syncthreads();
  const int Lmax = smax;
  int lenr[4];
#pragma unroll
  for (int r = 0; r < 4; ++r) lenr[r] = slen[4 * qd + r];

  // ---- emit prefetch offsets: rows m=4qd+r, cols j=32w+16u+c ----
  int off8[8];
#pragma unroll
  for (int r = 0; r < 4; ++r)
#pragma unroll
    for (int u = 0; u < 2; ++u)
      off8[r * 2 + u] = (bg + 4 * qd + r) * NN + 32 * w + 16 * u + c;

  float ra[8], rb[8], xv[8];
  {
    int t2 = (2 < TT) ? 2 : TT - 1;
#pragma unroll
    for (int i = 0; i < 8; ++i) ra[i] = emit[(size_t)1 * BB * NN + off8[i]];
#pragma unroll
    for (int i = 0; i < 8; ++i)
      rb[i] = emit[(size_t)t2 * BB * NN + off8[i]];
#pragma unroll
    for (int i = 0; i < 8; ++i) xv[i] = __expf(ra[i]);
  }
  int cloc[4] = {0, 0, 0, 0};
  const bool nwriter = (w == 0 && c == 0);

#define CRF_STEP(T_, PIN, POUT, RL, RO)                                       \
  do {                                                                        \
    int tl = ((T_) + 2 < TT) ? (T_) + 2 : TT - 1;                             \
    const size_t gbase = (size_t)tl * (BB * NN);                              \
    _Pragma("unroll") for (int i_ = 0; i_ < 8; ++i_)                          \
        RL[i_] = emit[gbase + off8[i_]];                                      \
    const short8_t A0 = *(const short8_t*)&sV[PIN][c * STH + 0 + qd * 8];     \
    const short8_t A1 = *(const short8_t*)&sV[PIN][c * STH + 32 + qd * 8];    \
    const short8_t A2 = *(const short8_t*)&sV[PIN][c * STH + 64 + qd * 8];    \
    const short8_t A3 = *(const short8_t*)&sV[PIN][c * STH + 96 + qd * 8];    \
    const int4 nr = *(const int4*)&nrm[PIN][4 * qd];                          \
    f32x4 ac0 = {0.f, 0.f, 0.f, 0.f}, ac1 = {0.f, 0.f, 0.f, 0.f};             \
    ac0 = __builtin_amdgcn_mfma_f32_16x16x32_bf16(A0, eB[0][0], ac0, 0, 0, 0);\
    ac1 = __builtin_amdgcn_mfma_f32_16x16x32_bf16(A0, eB[0][1], ac1, 0, 0, 0);\
    ac0 = __builtin_amdgcn_mfma_f32_16x16x32_bf16(A1, eB[1][0], ac0, 0, 0, 0);\
    ac1 = __builtin_amdgcn_mfma_f32_16x16x32_bf16(A1, eB[1][1], ac1, 0, 0, 0);\
    ac0 = __builtin_amdgcn_mfma_f32_16x16x32_bf16(A2, eB[2][0], ac0, 0, 0, 0);\
    ac1 = __builtin_amdgcn_mfma_f32_16x16x32_bf16(A2, eB[2][1], ac1, 0, 0, 0);\
    ac0 = __builtin_amdgcn_mfma_f32_16x16x32_bf16(A3, eB[3][0], ac0, 0, 0, 0);\
    ac1 = __builtin_amdgcn_mfma_f32_16x16x32_bf16(A3, eB[3][1], ac1, 0, 0, 0);\
    const int nA[4] = {nr.x, nr.y, nr.z, nr.w};                               \
    int nnw[4];                                                               \
    _Pragma("unroll") for (int r_ = 0; r_ < 4; ++r_) {                        \
      float y0 = ac0[r_] * xv[2 * r_];                                        \
      float y1 = ac1[r_] * xv[2 * r_ + 1];                                    \
      float v0 = ldexpf(y0, -nA[r_]);                                         \
      float v1 = ldexpf(y1, -nA[r_]);                                         \
      if ((T_) < lenr[r_]) {                                                  \
        unsigned pk = (unsigned)f2bf(v0) | ((unsigned)f2bf(v1) << 16);        \
        *(unsigned*)&sV[POUT][(4 * qd + r_) * STH + 32 * w + 2 * c] = pk;     \
        cloc[r_] += nA[r_];                                                   \
      }                                                                       \
      nnw[r_] = ((int)((__float_as_uint(v0) >> 23) & 0xFF)) - 120;            \
    }                                                                         \
    if (nwriter)                                                              \
      *(int4*)&nrm[POUT][4 * qd] = make_int4(nnw[0], nnw[1], nnw[2], nnw[3]); \
    _Pragma("unroll") for (int i_ = 0; i_ < 8; ++i_)                          \
        xv[i_] = __expf(RO[i_]);                                              \
    __syncthreads();                                                          \
  } while (0)

  for (int t = 1; t < Lmax; t += 2) {
    CRF_STEP(t, 0, 1, ra, rb);
    if (t + 1 < Lmax) {
      CRF_STEP(t + 1, 1, 0, rb, ra);
    }
  }
#undef CRF_STEP

  // ---- epilogue: per-chain logZ = C*ln2 + log(sum_j V_fin[m][j]*e^etrans) ----
  if (nwriter) *(int4*)&sC[4 * qd] = make_int4(cloc[0], cloc[1], cloc[2], cloc[3]);
  __syncthreads();
  {
    const int m = tid >> 4, i16 = tid & 15;
    const int pb = (slen[m] - 1) & 1;  // each chain's own final parity
    float s = 0.f;
#pragma unroll
    for (int pp = 0; pp < 8; ++pp) {
      int p = i16 * 8 + pp;
      int j = orig_j(p);
      s += bf2f(sV[pb][m * STH + p]) * __expf(etrans[j]);
    }
    s += __shfl_xor(s, 1, 64);
    s += __shfl_xor(s, 2, 64);
    s += __shfl_xor(s, 4, 64);
    s += __shfl_xor(s, 8, 64);
    if (i16 == 0)
      atomicAdd(&ws[0], (float)sC[m] * 0.69314718f + __logf(s));
  }
  __syncthreads();
  if (tid == 0) {
    __threadfence();
    unsigned old = atomicAdd((unsigned*)ws + 3, 1u);
    if (old == NWG - 1) {  // last workgroup publishes the result
      float zz = atomicAdd(&ws[0], 0.f);
      float ss = atomicAdd(&ws[1], 0.f);
      out[0] = (zz - ss) * (1.0f / (float)BB);
    }
  }
}

extern "C" void kernel_launch(void* const* d_in, const int* in_sizes, int n_in,
                              void* d_out, int out_size, void* d_ws, size_t ws_size,
                              hipStream_t stream) {
  const float* emit = (const float*)d_in[0];
  const int* target = (const int*)d_in[1];
  const void* mask = (const void*)d_in[2];
  const float* trans = (const float*)d_in[3];
  const float* strans = (const float*)d_in[4];
  const float* etrans = (const float*)d_in[5];
  float* ws = (float*)d_ws;
  float* out = (float*)d_out;

  hipMemsetAsync(d_ws, 0, 16, stream);
  crf_fused<<<NWG, 256, 0, stream>>>(emit, target, mask, trans, strans, etrans,
                                     ws, out);
}

// Round 6
// 361.611 us; speedup vs baseline: 1.1185x; 1.1185x over previous
//
#include <hip/hip_runtime.h>

#define TT 512
#define BB 256
#define NN 128
#define MW 16            // chains per workgroup (serial phase)
#define NWG (BB / MW)    // 16 workgroups
#define STH 144          // state row stride in halves (288 B, 16B-aligned)
#define XOFF 4096        // byte offset of X = exp(emit) table in ws

typedef __attribute__((ext_vector_type(8))) short short8_t;
typedef __attribute__((ext_vector_type(4))) float f32x4;

__device__ __forceinline__ unsigned short f2bf(float f) {
  unsigned u = __float_as_uint(f);
  return (unsigned short)((u + 0x7FFF + ((u >> 16) & 1)) >> 16);  // RNE
}
__device__ __forceinline__ float bf2f(unsigned short h) {
  return __uint_as_float(((unsigned)h) << 16);
}
// storage position p <-> original j:  j = 32w+16u+c  <->  p = 32w+2c+u
__device__ __forceinline__ int orig_j(int p) {
  return 32 * (p >> 5) + 16 * (p & 1) + ((p >> 1) & 15);
}

// ---------- Phase 1a: X[g][t][tid] = exp(emit) as bf16, consumer layout ----
// Thread tid of tile (g,t) stores the exact 8 bf16 values the phase-2 thread
// tid of workgroup g needs at step t, packed as one uint4.
__global__ __launch_bounds__(256) void crf_expemit(
    const float* __restrict__ emit, uint4* __restrict__ Xq) {
  const int bid = blockIdx.x;
  const int g = bid >> 9;        // / TT
  const int t = bid & (TT - 1);
  const int tid = threadIdx.x;
  const int w = tid >> 6, l = tid & 63, qd = l >> 4, c = l & 15;
  const int bg = g * MW;
  unsigned pk[4];
#pragma unroll
  for (int r = 0; r < 4; ++r) {
    const size_t row = ((size_t)t * BB + bg + 4 * qd + r) * NN + 32 * w + c;
    float v0 = __expf(emit[row]);
    float v1 = __expf(emit[row + 16]);
    pk[r] = (unsigned)f2bf(v0) | ((unsigned)f2bf(v1) << 16);
  }
  Xq[((size_t)g * TT + t) * 256 + tid] = make_uint4(pk[0], pk[1], pk[2], pk[3]);
}

// ---------- Phase 1b: gold score + per-chain lengths (parallel) ------------
__global__ __launch_bounds__(BB) void crf_score_k(
    const float* __restrict__ emit, const int* __restrict__ target,
    const void* __restrict__ maskp, const float* __restrict__ trans,
    const float* __restrict__ strans, const float* __restrict__ etrans,
    float* __restrict__ ws, int* __restrict__ lens) {
  __shared__ float rf[4];
  const int b = threadIdx.x;
  const int t = blockIdx.x;
  const unsigned char* mk8 = (const unsigned char*)maskp;
  const int* mk32 = (const int*)maskp;
  const bool is_u8 = (mk8[1] != 0);

  int m = is_u8 ? (mk8[t * BB + b] != 0) : (mk32[t * BB + b] != 0);
  float v = 0.f;
  if (m) {
    int tg = target[t * BB + b];
    v = emit[((size_t)t * BB + b) * NN + tg];
    v += (t > 0) ? trans[target[(t - 1) * BB + b] * NN + tg] : strans[tg];
    int mn = (t + 1 < TT) ? (is_u8 ? (mk8[(t + 1) * BB + b] != 0)
                                   : (mk32[(t + 1) * BB + b] != 0))
                          : 0;
    if (!mn) {  // prefix-mask edge = last valid step
      v += etrans[tg];
      lens[b] = t + 1;
    }
  }
#pragma unroll
  for (int off = 32; off; off >>= 1) v += __shfl_down(v, off, 64);
  if ((b & 63) == 0) rf[b >> 6] = v;
  __syncthreads();
  if (b == 0) atomicAdd(&ws[1], rf[0] + rf[1] + rf[2] + rf[3]);
}

// ---------- Phase 2: serial forward recursion, 16 chains per WG, MFMA ------
// Per step: 16x128x128 GEMM via 8 mfma_f32_16x16x32_bf16 per wave. State
// V[m][p] bf16 in LDS (double-buffered). E=exp(trans) bf16 B-fragments in
// VGPRs. Per-chain power-of-2 rescale, exact integer bookkeeping. X loads are
// hoisted to 8-step group prologues so the per-step barrier drain doesn't
// serialize HBM latency into every step.
__global__ __launch_bounds__(256, 1) void crf_forward_mfma(
    const float* __restrict__ emit, const float* __restrict__ trans,
    const float* __restrict__ strans, const float* __restrict__ etrans,
    const uint4* __restrict__ Xq, const int* __restrict__ lens,
    float* __restrict__ ws, float* __restrict__ out) {
  __shared__ __align__(16) unsigned short sV[2][MW * STH];
  __shared__ __align__(16) int nrm[2][MW];
  __shared__ __align__(16) int sC[MW];
  __shared__ int slen[MW];
  __shared__ int smax;

  const int tid = threadIdx.x;
  const int w = tid >> 6;   // wave: owns j-tiles {2w, 2w+1}
  const int l = tid & 63;
  const int c = l & 15;     // MFMA col (D) / A-row (A)
  const int qd = l >> 4;    // quad
  const int g = blockIdx.x;
  const int bg = g * MW;

  if (tid == 0) smax = 0;
  if (tid < MW) slen[tid] = lens[bg + tid];
  __syncthreads();
  if (tid < MW) atomicMax(&smax, slen[tid]);

  // ---- E B-fragments: eB[kt][u][jj] = E_perm[kt*32+qd*8+jj][32w+16u+c] ----
  short8_t eB[4][2];
#pragma unroll
  for (int kt = 0; kt < 4; ++kt)
#pragma unroll
    for (int u = 0; u < 2; ++u)
#pragma unroll
      for (int jj = 0; jj < 8; ++jj) {
        int kp = kt * 32 + qd * 8 + jj;
        int i = orig_j(kp);
        int j = 32 * w + 16 * u + c;
        eB[kt][u][jj] = (short)f2bf(__expf(trans[i * NN + j]));
      }

  // ---- init V_0[m][p] = exp(strans[j] + emit[0][b][j]) ----
  {
    const int m = tid & 15;
    const int b = bg + m;
    const int pbase = (tid >> 4) * 8;
#pragma unroll
    for (int pp = 0; pp < 8; ++pp) {
      int p = pbase + pp;
      int j = orig_j(p);
      float v = __expf(strans[j] + emit[(size_t)b * NN + j]);
      sV[0][m * STH + p] = f2bf(v);
      if (p == 0)
        nrm[0][m] = ((int)((__float_as_uint(v) >> 23) & 0xFF)) - 120;  // exp+7
    }
  }
  __syncthreads();
  const int Lmax = smax;
  int lenr[4];
#pragma unroll
  for (int r = 0; r < 4; ++r) lenr[r] = slen[4 * qd + r];

  int cloc[4] = {0, 0, 0, 0};
  const bool nwriter = (w == 0 && c == 0);
  const uint4* Xg = Xq + (size_t)g * TT * 256 + tid;

  for (int tb = 1; tb < Lmax; tb += 8) {
    // group prologue: fetch 8 steps of X (one dwordx4 per step per thread)
    uint4 xq[8];
#pragma unroll
    for (int k = 0; k < 8; ++k) {
      int t = tb + k;
      if (t > TT - 1) t = TT - 1;
      xq[k] = Xg[(size_t)t * 256];
    }
#pragma unroll
    for (int k = 0; k < 8; ++k) {
      const int T_ = tb + k;
      if (T_ >= Lmax) break;  // uniform across WG (Lmax is WG-uniform)
      const int PIN = k & 1;        // tb odd => state parity (T_-1)&1 == k&1
      const int POUT = (k + 1) & 1;

      const short8_t A0 = *(const short8_t*)&sV[PIN][c * STH + 0 + qd * 8];
      const short8_t A1 = *(const short8_t*)&sV[PIN][c * STH + 32 + qd * 8];
      const short8_t A2 = *(const short8_t*)&sV[PIN][c * STH + 64 + qd * 8];
      const short8_t A3 = *(const short8_t*)&sV[PIN][c * STH + 96 + qd * 8];
      const int4 nr = *(const int4*)&nrm[PIN][4 * qd];
      f32x4 ac0 = {0.f, 0.f, 0.f, 0.f}, ac1 = {0.f, 0.f, 0.f, 0.f};
      ac0 = __builtin_amdgcn_mfma_f32_16x16x32_bf16(A0, eB[0][0], ac0, 0, 0, 0);
      ac1 = __builtin_amdgcn_mfma_f32_16x16x32_bf16(A0, eB[0][1], ac1, 0, 0, 0);
      ac0 = __builtin_amdgcn_mfma_f32_16x16x32_bf16(A1, eB[1][0], ac0, 0, 0, 0);
      ac1 = __builtin_amdgcn_mfma_f32_16x16x32_bf16(A1, eB[1][1], ac1, 0, 0, 0);
      ac0 = __builtin_amdgcn_mfma_f32_16x16x32_bf16(A2, eB[2][0], ac0, 0, 0, 0);
      ac1 = __builtin_amdgcn_mfma_f32_16x16x32_bf16(A2, eB[2][1], ac1, 0, 0, 0);
      ac0 = __builtin_amdgcn_mfma_f32_16x16x32_bf16(A3, eB[3][0], ac0, 0, 0, 0);
      ac1 = __builtin_amdgcn_mfma_f32_16x16x32_bf16(A3, eB[3][1], ac1, 0, 0, 0);

      const int nA[4] = {nr.x, nr.y, nr.z, nr.w};
      const unsigned xd[4] = {xq[k].x, xq[k].y, xq[k].z, xq[k].w};
      int nnw[4];
#pragma unroll
      for (int r_ = 0; r_ < 4; ++r_) {
        float x0 = __uint_as_float(xd[r_] << 16);
        float x1 = __uint_as_float(xd[r_] & 0xffff0000u);
        float v0 = ldexpf(ac0[r_] * x0, -nA[r_]);
        float v1 = ldexpf(ac1[r_] * x1, -nA[r_]);
        if (T_ < lenr[r_]) {
          unsigned pk = (unsigned)f2bf(v0) | ((unsigned)f2bf(v1) << 16);
          *(unsigned*)&sV[POUT][(4 * qd + r_) * STH + 32 * w + 2 * c] = pk;
          cloc[r_] += nA[r_];
        }
        nnw[r_] = ((int)((__float_as_uint(v0) >> 23) & 0xFF)) - 120;
      }
      if (nwriter)
        *(int4*)&nrm[POUT][4 * qd] = make_int4(nnw[0], nnw[1], nnw[2], nnw[3]);
      __syncthreads();
    }
  }

  // ---- epilogue: per-chain logZ = C*ln2 + log(sum_j V_fin[m][j]*e^etrans) --
  if (nwriter) *(int4*)&sC[4 * qd] = make_int4(cloc[0], cloc[1], cloc[2], cloc[3]);
  __syncthreads();
  {
    const int m = tid >> 4, i16 = tid & 15;
    const int pb = (slen[m] - 1) & 1;  // each chain's own final parity
    float s = 0.f;
#pragma unroll
    for (int pp = 0; pp < 8; ++pp) {
      int p = i16 * 8 + pp;
      int j = orig_j(p);
      s += bf2f(sV[pb][m * STH + p]) * __expf(etrans[j]);
    }
    s += __shfl_xor(s, 1, 64);
    s += __shfl_xor(s, 2, 64);
    s += __shfl_xor(s, 4, 64);
    s += __shfl_xor(s, 8, 64);
    if (i16 == 0)
      atomicAdd(&ws[0], (float)sC[m] * 0.69314718f + __logf(s));
  }
  __syncthreads();
  if (tid == 0) {
    __threadfence();
    unsigned old = atomicAdd((unsigned*)ws + 3, 1u);
    if (old == NWG - 1) {  // last workgroup publishes the result
      float zz = atomicAdd(&ws[0], 0.f);
      float ss = atomicAdd(&ws[1], 0.f);
      out[0] = (zz - ss) * (1.0f / (float)BB);
    }
  }
}

// ---------- Fallback (Round-5 kernel, verified): used if ws too small ------
__global__ __launch_bounds__(256, 1) void crf_fused_fb(
    const float* __restrict__ emit, const int* __restrict__ target,
    const void* __restrict__ maskp, const float* __restrict__ trans,
    const float* __restrict__ strans, const float* __restrict__ etrans,
    float* __restrict__ ws, float* __restrict__ out) {
  __shared__ __align__(16) unsigned short sV[2][MW * STH];
  __shared__ __align__(16) int nrm[2][MW];
  __shared__ __align__(16) int sC[MW];
  __shared__ int slen[MW];
  __shared__ float sscore;
  __shared__ int smax;

  const int tid = threadIdx.x;
  const int w = tid >> 6;
  const int l = tid & 63;
  const int c = l & 15;
  const int qd = l >> 4;
  const int bg = blockIdx.x * MW;

  if (tid < MW) slen[tid] = 0;
  if (tid == 0) { sscore = 0.f; smax = 0; }
  __syncthreads();

  const unsigned char* mk8 = (const unsigned char*)maskp;
  const int* mk32 = (const int*)maskp;
  const bool is_u8 = (mk8[1] != 0);
  {
    const int mi = tid & 15;
    const int b = bg + mi;
    const int t0 = (tid >> 4) * 32;
    int cnt = 0;
    float sc = 0.f;
    for (int s = 0; s < 32; ++s) {
      int t = t0 + s;
      int m = is_u8 ? (mk8[t * BB + b] != 0) : (mk32[t * BB + b] != 0);
      if (m) {
        cnt++;
        int tg = target[t * BB + b];
        float v = emit[((size_t)t * BB + b) * NN + tg];
        v += (t > 0) ? trans[target[(t - 1) * BB + b] * NN + tg] : strans[tg];
        int mn = (t + 1 < TT) ? (is_u8 ? (mk8[(t + 1) * BB + b] != 0)
                                       : (mk32[(t + 1) * BB + b] != 0))
                              : 0;
        if (!mn) v += etrans[tg];
        sc += v;
      }
    }
    atomicAdd(&slen[mi], cnt);
    atomicAdd(&sscore, sc);
  }

  short8_t eB[4][2];
#pragma unroll
  for (int kt = 0; kt < 4; ++kt)
#pragma unroll
    for (int u = 0; u < 2; ++u)
#pragma unroll
      for (int jj = 0; jj < 8; ++jj) {
        int kp = kt * 32 + qd * 8 + jj;
        int i = orig_j(kp);
        int j = 32 * w + 16 * u + c;
        eB[kt][u][jj] = (short)f2bf(__expf(trans[i * NN + j]));
      }

  {
    const int m = tid & 15;
    const int b = bg + m;
    const int pbase = (tid >> 4) * 8;
#pragma unroll
    for (int pp = 0; pp < 8; ++pp) {
      int p = pbase + pp;
      int j = orig_j(p);
      float v = __expf(strans[j] + emit[(size_t)b * NN + j]);
      sV[0][m * STH + p] = f2bf(v);
      if (p == 0)
        nrm[0][m] = ((int)((__float_as_uint(v) >> 23) & 0xFF)) - 120;
    }
  }
  __syncthreads();

  if (tid < MW) atomicMax(&smax, slen[tid]);
  if (tid == 0) atomicAdd(&ws[1], sscore);
  __syncthreads();
  const int Lmax = smax;
  int lenr[4];
#pragma unroll
  for (int r = 0; r < 4; ++r) lenr[r] = slen[4 * qd + r];

  int off8[8];
#pragma unroll
  for (int r = 0; r < 4; ++r)
#pragma unroll
    for (int u = 0; u < 2; ++u)
      off8[r * 2 + u] = (bg + 4 * qd + r) * NN + 32 * w + 16 * u + c;

  float ra[8], rb[8], xv[8];
  {
    int t2 = (2 < TT) ? 2 : TT - 1;
#pragma unroll
    for (int i = 0; i < 8; ++i) ra[i] = emit[(size_t)1 * BB * NN + off8[i]];
#pragma unroll
    for (int i = 0; i < 8; ++i) rb[i] = emit[(size_t)t2 * BB * NN + off8[i]];
#pragma unroll
    for (int i = 0; i < 8; ++i) xv[i] = __expf(ra[i]);
  }
  int cloc[4] = {0, 0, 0, 0};
  const bool nwriter = (w == 0 && c == 0);

#define CRF_STEP(T_, PIN, POUT, RL, RO)                                       \
  do {                                                                        \
    int tl = ((T_) + 2 < TT) ? (T_) + 2 : TT - 1;                             \
    const size_t gbase = (size_t)tl * (BB * NN);                              \
    _Pragma("unroll") for (int i_ = 0; i_ < 8; ++i_)                          \
        RL[i_] = emit[gbase + off8[i_]];                                      \
    const short8_t A0 = *(const short8_t*)&sV[PIN][c * STH + 0 + qd * 8];     \
    const short8_t A1 = *(const short8_t*)&sV[PIN][c * STH + 32 + qd * 8];    \
    const short8_t A2 = *(const short8_t*)&sV[PIN][c * STH + 64 + qd * 8];    \
    const short8_t A3 = *(const short8_t*)&sV[PIN][c * STH + 96 + qd * 8];    \
    const int4 nr = *(const int4*)&nrm[PIN][4 * qd];                          \
    f32x4 ac0 = {0.f, 0.f, 0.f, 0.f}, ac1 = {0.f, 0.f, 0.f, 0.f};             \
    ac0 = __builtin_amdgcn_mfma_f32_16x16x32_bf16(A0, eB[0][0], ac0, 0, 0, 0);\
    ac1 = __builtin_amdgcn_mfma_f32_16x16x32_bf16(A0, eB[0][1], ac1, 0, 0, 0);\
    ac0 = __builtin_amdgcn_mfma_f32_16x16x32_bf16(A1, eB[1][0], ac0, 0, 0, 0);\
    ac1 = __builtin_amdgcn_mfma_f32_16x16x32_bf16(A1, eB[1][1], ac1, 0, 0, 0);\
    ac0 = __builtin_amdgcn_mfma_f32_16x16x32_bf16(A2, eB[2][0], ac0, 0, 0, 0);\
    ac1 = __builtin_amdgcn_mfma_f32_16x16x32_bf16(A2, eB[2][1], ac1, 0, 0, 0);\
    ac0 = __builtin_amdgcn_mfma_f32_16x16x32_bf16(A3, eB[3][0], ac0, 0, 0, 0);\
    ac1 = __builtin_amdgcn_mfma_f32_16x16x32_bf16(A3, eB[3][1], ac1, 0, 0, 0);\
    const int nA[4] = {nr.x, nr.y, nr.z, nr.w};                               \
    int nnw[4];                                                               \
    _Pragma("unroll") for (int r_ = 0; r_ < 4; ++r_) {                        \
      float y0 = ac0[r_] * xv[2 * r_];                                        \
      float y1 = ac1[r_] * xv[2 * r_ + 1];                                    \
      float v0 = ldexpf(y0, -nA[r_]);                                         \
      float v1 = ldexpf(y1, -nA[r_]);                                         \
      if ((T_) < lenr[r_]) {                                                  \
        unsigned pk = (unsigned)f2bf(v0) | ((unsigned)f2bf(v1) << 16);        \
        *(unsigned*)&sV[POUT][(4 * qd + r_) * STH + 32 * w + 2 * c] = pk;     \
        cloc[r_] += nA[r_];                                                   \
      }                                                                       \
      nnw[r_] = ((int)((__float_as_uint(v0) >> 23) & 0xFF)) - 120;            \
    }                                                                         \
    if (nwriter)                                                              \
      *(int4*)&nrm[POUT][4 * qd] = make_int4(nnw[0], nnw[1], nnw[2], nnw[3]); \
    _Pragma("unroll") for (int i_ = 0; i_ < 8; ++i_)                          \
        xv[i_] = __expf(RO[i_]);                                              \
    __syncthreads();                                                          \
  } while (0)

  for (int t = 1; t < Lmax; t += 2) {
    CRF_STEP(t, 0, 1, ra, rb);
    if (t + 1 < Lmax) {
      CRF_STEP(t + 1, 1, 0, rb, ra);
    }
  }
#undef CRF_STEP

  if (nwriter) *(int4*)&sC[4 * qd] = make_int4(cloc[0], cloc[1], cloc[2], cloc[3]);
  __syncthreads();
  {
    const int m = tid >> 4, i16 = tid & 15;
    const int pb = (slen[m] - 1) & 1;
    float s = 0.f;
#pragma unroll
    for (int pp = 0; pp < 8; ++pp) {
      int p = i16 * 8 + pp;
      int j = orig_j(p);
      s += bf2f(sV[pb][m * STH + p]) * __expf(etrans[j]);
    }
    s += __shfl_xor(s, 1, 64);
    s += __shfl_xor(s, 2, 64);
    s += __shfl_xor(s, 4, 64);
    s += __shfl_xor(s, 8, 64);
    if (i16 == 0)
      atomicAdd(&ws[0], (float)sC[m] * 0.69314718f + __logf(s));
  }
  __syncthreads();
  if (tid == 0) {
    __threadfence();
    unsigned old = atomicAdd((unsigned*)ws + 3, 1u);
    if (old == NWG - 1) {
      float zz = atomicAdd(&ws[0], 0.f);
      float ss = atomicAdd(&ws[1], 0.f);
      out[0] = (zz - ss) * (1.0f / (float)BB);
    }
  }
}

extern "C" void kernel_launch(void* const* d_in, const int* in_sizes, int n_in,
                              void* d_out, int out_size, void* d_ws, size_t ws_size,
                              hipStream_t stream) {
  const float* emit = (const float*)d_in[0];
  const int* target = (const int*)d_in[1];
  const void* mask = (const void*)d_in[2];
  const float* trans = (const float*)d_in[3];
  const float* strans = (const float*)d_in[4];
  const float* etrans = (const float*)d_in[5];
  float* ws = (float*)d_ws;
  float* out = (float*)d_out;

  const size_t need = (size_t)XOFF + (size_t)TT * BB * NN * 2;
  hipMemsetAsync(d_ws, 0, 16, stream);
  if (ws_size >= need) {
    int* lens = (int*)((char*)d_ws + 64);
    uint4* Xq = (uint4*)((char*)d_ws + XOFF);
    crf_expemit<<<NWG * TT, 256, 0, stream>>>(emit, Xq);
    crf_score_k<<<TT, BB, 0, stream>>>(emit, target, mask, trans, strans,
                                       etrans, ws, lens);
    crf_forward_mfma<<<NWG, 256, 0, stream>>>(emit, trans, strans, etrans,
                                              (const uint4*)Xq, lens, ws, out);
  } else {
    crf_fused_fb<<<NWG, 256, 0, stream>>>(emit, target, mask, trans, strans,
                                          etrans, ws, out);
  }
}

// Round 7
// 259.207 us; speedup vs baseline: 1.5604x; 1.3951x over previous
//
#include <hip/hip_runtime.h>

#define TT 512
#define BB 256
#define NN 128
#define MW 16            // chains per workgroup (serial phase)
#define NWG (BB / MW)    // 16 chain-groups
#define STH 144          // state row stride in halves (288 B, 16B-aligned)

// ws layout (bytes)
#define LENS_OFF 256
#define AF_OFF 2048
#define CF_OFF (AF_OFF + BB * NN * 4)
#define BU_OFF (CF_OFF + 1024)
#define CB_OFF (BU_OFF + BB * NN * 4)
#define XQ_OFF (CB_OFF + 1024)
#define XQ_SZ ((size_t)TT * BB * NN * 2)

typedef __attribute__((ext_vector_type(8))) short short8_t;
typedef __attribute__((ext_vector_type(4))) float f32x4;

__device__ __forceinline__ unsigned short f2bf(float f) {
  unsigned u = __float_as_uint(f);
  return (unsigned short)((u + 0x7FFF + ((u >> 16) & 1)) >> 16);  // RNE
}
__device__ __forceinline__ float bf2f(unsigned short h) {
  return __uint_as_float(((unsigned)h) << 16);
}
// storage position p <-> original index:  idx = 32w+16u+c  <->  p = 32w+2c+u
__device__ __forceinline__ int orig_j(int p) {
  return 32 * (p >> 5) + 16 * (p & 1) + ((p >> 1) & 15);
}

// ---------- Phase 1a: X[g][t][tid] = exp(emit) as bf16, consumer layout ----
__global__ __launch_bounds__(256) void crf_expemit(
    const float* __restrict__ emit, uint4* __restrict__ Xq) {
  const int bid = blockIdx.x;
  const int g = bid >> 9;
  const int t = bid & (TT - 1);
  const int tid = threadIdx.x;
  const int w = tid >> 6, l = tid & 63, qd = l >> 4, c = l & 15;
  const int bg = g * MW;
  unsigned pk[4];
#pragma unroll
  for (int r = 0; r < 4; ++r) {
    const size_t row = ((size_t)t * BB + bg + 4 * qd + r) * NN + 32 * w + c;
    float v0 = __expf(emit[row]);
    float v1 = __expf(emit[row + 16]);
    pk[r] = (unsigned)f2bf(v0) | ((unsigned)f2bf(v1) << 16);
  }
  Xq[((size_t)g * TT + t) * 256 + tid] = make_uint4(pk[0], pk[1], pk[2], pk[3]);
}

// ---------- Phase 1b: gold score + per-chain lengths (parallel) ------------
__global__ __launch_bounds__(BB) void crf_score_k(
    const float* __restrict__ emit, const int* __restrict__ target,
    const void* __restrict__ maskp, const float* __restrict__ trans,
    const float* __restrict__ strans, const float* __restrict__ etrans,
    float* __restrict__ ws, int* __restrict__ lens) {
  __shared__ float rf[4];
  const int b = threadIdx.x;
  const int t = blockIdx.x;
  const unsigned char* mk8 = (const unsigned char*)maskp;
  const int* mk32 = (const int*)maskp;
  const bool is_u8 = (mk8[1] != 0);

  int m = is_u8 ? (mk8[t * BB + b] != 0) : (mk32[t * BB + b] != 0);
  float v = 0.f;
  if (m) {
    int tg = target[t * BB + b];
    v = emit[((size_t)t * BB + b) * NN + tg];
    v += (t > 0) ? trans[target[(t - 1) * BB + b] * NN + tg] : strans[tg];
    int mn = (t + 1 < TT) ? (is_u8 ? (mk8[(t + 1) * BB + b] != 0)
                                   : (mk32[(t + 1) * BB + b] != 0))
                          : 0;
    if (!mn) {  // prefix-mask edge = last valid step
      v += etrans[tg];
      lens[b] = t + 1;
    }
  }
#pragma unroll
  for (int off = 32; off; off >>= 1) v += __shfl_down(v, off, 64);
  if ((b & 63) == 0) rf[b >> 6] = v;
  __syncthreads();
  if (b == 0) atomicAdd(&ws[1], rf[0] + rf[1] + rf[2] + rf[3]);
}

// ---------- Phase 2: fwd (blocks 0..15) + bwd (blocks 16..31) recursions ---
// Forward: alpha-recursion t=1..min(len-1,257), as R6.
// Backward: U_t = x_t . beta_t;  U' = x_t . (E U);  activation at t=len-1
// with U = x . exp(etrans); runs t = smax-1 down to 258. Identical step body
// (E transposed at load, x applied on the output side in both directions).
__global__ __launch_bounds__(256, 1) void crf_fb(
    const float* __restrict__ emit, const float* __restrict__ trans,
    const float* __restrict__ strans, const float* __restrict__ etrans,
    const uint4* __restrict__ Xq, const int* __restrict__ lens,
    float* __restrict__ AF, int* __restrict__ CF,
    float* __restrict__ BU, int* __restrict__ CB) {
  __shared__ __align__(16) unsigned short sV[2][MW * STH];
  __shared__ __align__(16) int nrm[2][MW];
  __shared__ __align__(16) int sC[MW];
  __shared__ int slen[MW];
  __shared__ int smax_s;

  const int tid = threadIdx.x;
  const int w = tid >> 6;
  const int l = tid & 63;
  const int c = l & 15;
  const int qd = l >> 4;
  const bool bwd = (blockIdx.x >= NWG);
  const int g = bwd ? (int)blockIdx.x - NWG : (int)blockIdx.x;
  const int bg = g * MW;

  if (tid == 0) smax_s = 0;
  if (tid < MW) slen[tid] = lens[bg + tid];
  __syncthreads();
  if (tid < MW) atomicMax(&smax_s, slen[tid]);

  // ---- E fragments (bwd: transposed orientation) ----
  short8_t eB[4][2];
#pragma unroll
  for (int kt = 0; kt < 4; ++kt)
#pragma unroll
    for (int u = 0; u < 2; ++u)
#pragma unroll
      for (int jj = 0; jj < 8; ++jj) {
        int kp = kt * 32 + qd * 8 + jj;
        int a_ = orig_j(kp);
        int b_ = 32 * w + 16 * u + c;
        float tv = bwd ? trans[b_ * NN + a_] : trans[a_ * NN + b_];
        eB[kt][u][jj] = (short)f2bf(__expf(tv));
      }
  const float eet0 = __expf(etrans[32 * w + c]);
  const float eet1 = __expf(etrans[32 * w + 16 + c]);

  // ---- init state ----
  {
    const int m = tid & 15;
    const int pbase = (tid >> 4) * 8;
    if (!bwd) {
      const int b = bg + m;
#pragma unroll
      for (int pp = 0; pp < 8; ++pp) {
        int p = pbase + pp;
        int j = orig_j(p);
        float v = __expf(strans[j] + emit[(size_t)b * NN + j]);
        sV[0][m * STH + p] = f2bf(v);
        if (p == 0)
          nrm[0][m] = ((int)((__float_as_uint(v) >> 23) & 0xFF)) - 120;
      }
    } else {
#pragma unroll
      for (int pp = 0; pp < 8; ++pp) {
        int p = pbase + pp;
        sV[0][m * STH + p] = 0x3F80;  // 1.0 bf16
        sV[1][m * STH + p] = 0x3F80;
        if (p == 0) { nrm[0][m] = 0; nrm[1][m] = 0; }
      }
    }
  }
  __syncthreads();
  const int smax = smax_s;
  int lm1[4];
#pragma unroll
  for (int r = 0; r < 4; ++r) lm1[r] = slen[4 * qd + r] - 1;

  int cloc[4] = {0, 0, 0, 0};
  const bool nwriter = (w == 0 && c == 0);
  const uint4* Xg = Xq + (size_t)g * TT * 256 + tid;

#define FB_MFMA()                                                             \
    const short8_t A0 = *(const short8_t*)&sV[PIN][c * STH + 0 + qd * 8];     \
    const short8_t A1 = *(const short8_t*)&sV[PIN][c * STH + 32 + qd * 8];    \
    const short8_t A2 = *(const short8_t*)&sV[PIN][c * STH + 64 + qd * 8];    \
    const short8_t A3 = *(const short8_t*)&sV[PIN][c * STH + 96 + qd * 8];    \
    const int4 nr = *(const int4*)&nrm[PIN][4 * qd];                          \
    f32x4 p0 = {0.f, 0.f, 0.f, 0.f}, q0 = {0.f, 0.f, 0.f, 0.f};              \
    f32x4 p1 = {0.f, 0.f, 0.f, 0.f}, q1 = {0.f, 0.f, 0.f, 0.f};              \
    p0 = __builtin_amdgcn_mfma_f32_16x16x32_bf16(A0, eB[0][0], p0, 0, 0, 0); \
    p1 = __builtin_amdgcn_mfma_f32_16x16x32_bf16(A0, eB[0][1], p1, 0, 0, 0); \
    q0 = __builtin_amdgcn_mfma_f32_16x16x32_bf16(A2, eB[2][0], q0, 0, 0, 0); \
    q1 = __builtin_amdgcn_mfma_f32_16x16x32_bf16(A2, eB[2][1], q1, 0, 0, 0); \
    p0 = __builtin_amdgcn_mfma_f32_16x16x32_bf16(A1, eB[1][0], p0, 0, 0, 0); \
    p1 = __builtin_amdgcn_mfma_f32_16x16x32_bf16(A1, eB[1][1], p1, 0, 0, 0); \
    q0 = __builtin_amdgcn_mfma_f32_16x16x32_bf16(A3, eB[3][0], q0, 0, 0, 0); \
    q1 = __builtin_amdgcn_mfma_f32_16x16x32_bf16(A3, eB[3][1], q1, 0, 0, 0); \
    const f32x4 ac0 = p0 + q0;                                                \
    const f32x4 ac1 = p1 + q1;                                                \
    const int nA[4] = {nr.x, nr.y, nr.z, nr.w};

  if (!bwd) {
    const int LmaxF = (smax < 258) ? smax : 258;  // steps t <= 257
    for (int tb = 1; tb < LmaxF; tb += 8) {
      uint4 xq[8];
#pragma unroll
      for (int k = 0; k < 8; ++k) {
        int t = tb + k;
        if (t > TT - 1) t = TT - 1;
        xq[k] = Xg[(size_t)t * 256];
      }
#pragma unroll
      for (int k = 0; k < 8; ++k) {
        const int T_ = tb + k;
        if (T_ >= LmaxF) break;
        const int POUT = T_ & 1, PIN = POUT ^ 1;
        FB_MFMA();
        const unsigned xd[4] = {xq[k].x, xq[k].y, xq[k].z, xq[k].w};
        int nnw[4];
#pragma unroll
        for (int r_ = 0; r_ < 4; ++r_) {
          float x0 = __uint_as_float(xd[r_] << 16);
          float x1 = __uint_as_float(xd[r_] & 0xffff0000u);
          float v0 = ldexpf(ac0[r_] * x0, -nA[r_]);
          float v1 = ldexpf(ac1[r_] * x1, -nA[r_]);
          if (T_ <= lm1[r_]) {
            unsigned pk = (unsigned)f2bf(v0) | ((unsigned)f2bf(v1) << 16);
            *(unsigned*)&sV[POUT][(4 * qd + r_) * STH + 32 * w + 2 * c] = pk;
            cloc[r_] += nA[r_];
          }
          nnw[r_] = ((int)((__float_as_uint(v0) >> 23) & 0xFF)) - 120;
        }
        if (nwriter)
          *(int4*)&nrm[POUT][4 * qd] = make_int4(nnw[0], nnw[1], nnw[2], nnw[3]);
        __syncthreads();
      }
    }
  } else if (smax >= 259) {
    for (int tb = smax - 1; tb >= 258; tb -= 8) {
      uint4 xq[8];
#pragma unroll
      for (int k = 0; k < 8; ++k) {
        int t = tb - k;
        if (t < 258) t = 258;
        xq[k] = Xg[(size_t)t * 256];
      }
#pragma unroll
      for (int k = 0; k < 8; ++k) {
        const int T_ = tb - k;
        if (T_ < 258) break;
        const int POUT = T_ & 1, PIN = POUT ^ 1;
        FB_MFMA();
        const unsigned xd[4] = {xq[k].x, xq[k].y, xq[k].z, xq[k].w};
        int nnw[4];
#pragma unroll
        for (int r_ = 0; r_ < 4; ++r_) {
          float x0 = __uint_as_float(xd[r_] << 16);
          float x1 = __uint_as_float(xd[r_] & 0xffff0000u);
          const bool isact = (T_ == lm1[r_]);
          float v0 = isact ? x0 * eet0 : ldexpf(ac0[r_] * x0, -nA[r_]);
          float v1 = isact ? x1 * eet1 : ldexpf(ac1[r_] * x1, -nA[r_]);
          if (T_ <= lm1[r_]) {
            unsigned pk = (unsigned)f2bf(v0) | ((unsigned)f2bf(v1) << 16);
            *(unsigned*)&sV[POUT][(4 * qd + r_) * STH + 32 * w + 2 * c] = pk;
            cloc[r_] = isact ? 0 : cloc[r_] + nA[r_];
          }
          nnw[r_] = ((int)((__float_as_uint(v0) >> 23) & 0xFF)) - 120;
        }
        if (nwriter)
          *(int4*)&nrm[POUT][4 * qd] = make_int4(nnw[0], nnw[1], nnw[2], nnw[3]);
        __syncthreads();
      }
    }
  }
#undef FB_MFMA

  // ---- epilogue: dump per-chain state + pow2 counters to global ----
  if (nwriter)
    *(int4*)&sC[4 * qd] = make_int4(cloc[0], cloc[1], cloc[2], cloc[3]);
  __syncthreads();
  {
    const int m = tid >> 4, i16 = tid & 15;
    if (!bwd) {
      int nf = slen[m] - 1;
      if (nf > 257) nf = 257;
      const int pf = nf & 1;
#pragma unroll
      for (int pp = 0; pp < 8; ++pp) {
        int p = i16 * 8 + pp;
        AF[(size_t)(bg + m) * NN + p] = bf2f(sV[pf][m * STH + p]);
      }
      if (i16 == 0) CF[bg + m] = sC[m];
    } else {
      // active chains all end at t=258 -> parity 0; inactive: init (unused)
#pragma unroll
      for (int pp = 0; pp < 8; ++pp) {
        int p = i16 * 8 + pp;
        BU[(size_t)(bg + m) * NN + p] = bf2f(sV[0][m * STH + p]);
      }
      if (i16 == 0) CB[bg + m] = sC[m];
    }
  }
}

// ---------- Phase 3: combine.  logZ_b = ln2*(CF+CB) + ln(alpha_257 . E U_258)
// (len>=259) or ln2*CF + ln(alpha . exp(etrans)) (len<=258). ----------------
__global__ __launch_bounds__(256) void crf_comb(
    const float* __restrict__ trans, const float* __restrict__ etrans,
    const int* __restrict__ lens, const float* __restrict__ AF,
    const int* __restrict__ CF, const float* __restrict__ BU,
    const int* __restrict__ CB, float* __restrict__ ws,
    float* __restrict__ out) {
  __shared__ __align__(16) unsigned short sU[MW * STH];
  __shared__ float sRed[4][MW][2];
  __shared__ int slen[MW];
  const int tid = threadIdx.x;
  const int w = tid >> 6, l = tid & 63, c = l & 15, qd = l >> 4;
  const int g = blockIdx.x, bg = g * MW;

  if (tid < MW) slen[tid] = lens[bg + tid];
  {
    const int m = tid & 15, pbase = (tid >> 4) * 8;
#pragma unroll
    for (int pp = 0; pp < 8; ++pp) {
      int p = pbase + pp;
      sU[m * STH + p] = f2bf(BU[(size_t)(bg + m) * NN + p]);
    }
  }
  short8_t eB[4][2];
#pragma unroll
  for (int kt = 0; kt < 4; ++kt)
#pragma unroll
    for (int u = 0; u < 2; ++u)
#pragma unroll
      for (int jj = 0; jj < 8; ++jj) {
        int kp = kt * 32 + qd * 8 + jj;
        int a_ = orig_j(kp);
        int b_ = 32 * w + 16 * u + c;
        eB[kt][u][jj] = (short)f2bf(__expf(trans[b_ * NN + a_]));  // bwd orient
      }
  const float eet0 = __expf(etrans[32 * w + c]);
  const float eet1 = __expf(etrans[32 * w + 16 + c]);
  __syncthreads();

  const short8_t A0 = *(const short8_t*)&sU[c * STH + 0 + qd * 8];
  const short8_t A1 = *(const short8_t*)&sU[c * STH + 32 + qd * 8];
  const short8_t A2 = *(const short8_t*)&sU[c * STH + 64 + qd * 8];
  const short8_t A3 = *(const short8_t*)&sU[c * STH + 96 + qd * 8];
  f32x4 ac0 = {0.f, 0.f, 0.f, 0.f}, ac1 = {0.f, 0.f, 0.f, 0.f};
  ac0 = __builtin_amdgcn_mfma_f32_16x16x32_bf16(A0, eB[0][0], ac0, 0, 0, 0);
  ac1 = __builtin_amdgcn_mfma_f32_16x16x32_bf16(A0, eB[0][1], ac1, 0, 0, 0);
  ac0 = __builtin_amdgcn_mfma_f32_16x16x32_bf16(A1, eB[1][0], ac0, 0, 0, 0);
  ac1 = __builtin_amdgcn_mfma_f32_16x16x32_bf16(A1, eB[1][1], ac1, 0, 0, 0);
  ac0 = __builtin_amdgcn_mfma_f32_16x16x32_bf16(A2, eB[2][0], ac0, 0, 0, 0);
  ac1 = __builtin_amdgcn_mfma_f32_16x16x32_bf16(A2, eB[2][1], ac1, 0, 0, 0);
  ac0 = __builtin_amdgcn_mfma_f32_16x16x32_bf16(A3, eB[3][0], ac0, 0, 0, 0);
  ac1 = __builtin_amdgcn_mfma_f32_16x16x32_bf16(A3, eB[3][1], ac1, 0, 0, 0);

#pragma unroll
  for (int r_ = 0; r_ < 4; ++r_) {
    // alpha at cols i0 = 32w+c (p=32w+2c), i1 = 32w+16+c (p=32w+2c+1)
    float a0 = AF[(size_t)(bg + 4 * qd + r_) * NN + 32 * w + 2 * c];
    float a1 = AF[(size_t)(bg + 4 * qd + r_) * NN + 32 * w + 2 * c + 1];
    float dB = a0 * ac0[r_] + a1 * ac1[r_];
    float dA = a0 * eet0 + a1 * eet1;
#pragma unroll
    for (int mk = 1; mk < 16; mk <<= 1) {
      dB += __shfl_xor(dB, mk, 64);
      dA += __shfl_xor(dA, mk, 64);
    }
    if (c == 0) {
      sRed[w][4 * qd + r_][0] = dB;
      sRed[w][4 * qd + r_][1] = dA;
    }
  }
  __syncthreads();
  if (tid < MW) {
    float DB = sRed[0][tid][0] + sRed[1][tid][0] + sRed[2][tid][0] + sRed[3][tid][0];
    float DA = sRed[0][tid][1] + sRed[1][tid][1] + sRed[2][tid][1] + sRed[3][tid][1];
    const int len = slen[tid];
    const float LN2 = 0.6931471805599453f;
    float logZ;
    if (len >= 259)
      logZ = LN2 * (float)(CF[bg + tid] + CB[bg + tid]) + __logf(DB);
    else
      logZ = LN2 * (float)CF[bg + tid] + __logf(DA);
    atomicAdd(&ws[0], logZ);
  }
  __syncthreads();
  if (tid == 0) {
    __threadfence();
    unsigned old = atomicAdd((unsigned*)ws + 3, 1u);
    if (old == NWG - 1) {
      float zz = atomicAdd(&ws[0], 0.f);
      float ss = atomicAdd(&ws[1], 0.f);
      out[0] = (zz - ss) * (1.0f / (float)BB);
    }
  }
}

// ---------- Fallback (Round-5 fused kernel, verified) ----------------------
__global__ __launch_bounds__(256, 1) void crf_fused_fb(
    const float* __restrict__ emit, const int* __restrict__ target,
    const void* __restrict__ maskp, const float* __restrict__ trans,
    const float* __restrict__ strans, const float* __restrict__ etrans,
    float* __restrict__ ws, float* __restrict__ out) {
  __shared__ __align__(16) unsigned short sV[2][MW * STH];
  __shared__ __align__(16) int nrm[2][MW];
  __shared__ __align__(16) int sC[MW];
  __shared__ int slen[MW];
  __shared__ float sscore;
  __shared__ int smax;

  const int tid = threadIdx.x;
  const int w = tid >> 6;
  const int l = tid & 63;
  const int c = l & 15;
  const int qd = l >> 4;
  const int bg = blockIdx.x * MW;

  if (tid < MW) slen[tid] = 0;
  if (tid == 0) { sscore = 0.f; smax = 0; }
  __syncthreads();

  const unsigned char* mk8 = (const unsigned char*)maskp;
  const int* mk32 = (const int*)maskp;
  const bool is_u8 = (mk8[1] != 0);
  {
    const int mi = tid & 15;
    const int b = bg + mi;
    const int t0 = (tid >> 4) * 32;
    int cnt = 0;
    float sc = 0.f;
    for (int s = 0; s < 32; ++s) {
      int t = t0 + s;
      int m = is_u8 ? (mk8[t * BB + b] != 0) : (mk32[t * BB + b] != 0);
      if (m) {
        cnt++;
        int tg = target[t * BB + b];
        float v = emit[((size_t)t * BB + b) * NN + tg];
        v += (t > 0) ? trans[target[(t - 1) * BB + b] * NN + tg] : strans[tg];
        int mn = (t + 1 < TT) ? (is_u8 ? (mk8[(t + 1) * BB + b] != 0)
                                       : (mk32[(t + 1) * BB + b] != 0))
                              : 0;
        if (!mn) v += etrans[tg];
        sc += v;
      }
    }
    atomicAdd(&slen[mi], cnt);
    atomicAdd(&sscore, sc);
  }

  short8_t eB[4][2];
#pragma unroll
  for (int kt = 0; kt < 4; ++kt)
#pragma unroll
    for (int u = 0; u < 2; ++u)
#pragma unroll
      for (int jj = 0; jj < 8; ++jj) {
        int kp = kt * 32 + qd * 8 + jj;
        int i = orig_j(kp);
        int j = 32 * w + 16 * u + c;
        eB[kt][u][jj] = (short)f2bf(__expf(trans[i * NN + j]));
      }

  {
    const int m = tid & 15;
    const int b = bg + m;
    const int pbase = (tid >> 4) * 8;
#pragma unroll
    for (int pp = 0; pp < 8; ++pp) {
      int p = pbase + pp;
      int j = orig_j(p);
      float v = __expf(strans[j] + emit[(size_t)b * NN + j]);
      sV[0][m * STH + p] = f2bf(v);
      if (p == 0)
        nrm[0][m] = ((int)((__float_as_uint(v) >> 23) & 0xFF)) - 120;
    }
  }
  __syncthreads();

  if (tid < MW) atomicMax(&smax, slen[tid]);
  if (tid == 0) atomicAdd(&ws[1], sscore);
  __syncthreads();
  const int Lmax = smax;
  int lenr[4];
#pragma unroll
  for (int r = 0; r < 4; ++r) lenr[r] = slen[4 * qd + r];

  int off8[8];
#pragma unroll
  for (int r = 0; r < 4; ++r)
#pragma unroll
    for (int u = 0; u < 2; ++u)
      off8[r * 2 + u] = (bg + 4 * qd + r) * NN + 32 * w + 16 * u + c;

  float ra[8], rb[8], xv[8];
  {
#pragma unroll
    for (int i = 0; i < 8; ++i) ra[i] = emit[(size_t)1 * BB * NN + off8[i]];
#pragma unroll
    for (int i = 0; i < 8; ++i) rb[i] = emit[(size_t)2 * BB * NN + off8[i]];
#pragma unroll
    for (int i = 0; i < 8; ++i) xv[i] = __expf(ra[i]);
  }
  int cloc[4] = {0, 0, 0, 0};
  const bool nwriter = (w == 0 && c == 0);

#define CRF_STEP(T_, PIN, POUT, RL, RO)                                       \
  do {                                                                        \
    int tl = ((T_) + 2 < TT) ? (T_) + 2 : TT - 1;                             \
    const size_t gbase = (size_t)tl * (BB * NN);                              \
    _Pragma("unroll") for (int i_ = 0; i_ < 8; ++i_)                          \
        RL[i_] = emit[gbase + off8[i_]];                                      \
    const short8_t A0 = *(const short8_t*)&sV[PIN][c * STH + 0 + qd * 8];     \
    const short8_t A1 = *(const short8_t*)&sV[PIN][c * STH + 32 + qd * 8];    \
    const short8_t A2 = *(const short8_t*)&sV[PIN][c * STH + 64 + qd * 8];    \
    const short8_t A3 = *(const short8_t*)&sV[PIN][c * STH + 96 + qd * 8];    \
    const int4 nr = *(const int4*)&nrm[PIN][4 * qd];                          \
    f32x4 ac0 = {0.f, 0.f, 0.f, 0.f}, ac1 = {0.f, 0.f, 0.f, 0.f};             \
    ac0 = __builtin_amdgcn_mfma_f32_16x16x32_bf16(A0, eB[0][0], ac0, 0, 0, 0);\
    ac1 = __builtin_amdgcn_mfma_f32_16x16x32_bf16(A0, eB[0][1], ac1, 0, 0, 0);\
    ac0 = __builtin_amdgcn_mfma_f32_16x16x32_bf16(A1, eB[1][0], ac0, 0, 0, 0);\
    ac1 = __builtin_amdgcn_mfma_f32_16x16x32_bf16(A1, eB[1][1], ac1, 0, 0, 0);\
    ac0 = __builtin_amdgcn_mfma_f32_16x16x32_bf16(A2, eB[2][0], ac0, 0, 0, 0);\
    ac1 = __builtin_amdgcn_mfma_f32_16x16x32_bf16(A2, eB[2][1], ac1, 0, 0, 0);\
    ac0 = __builtin_amdgcn_mfma_f32_16x16x32_bf16(A3, eB[3][0], ac0, 0, 0, 0);\
    ac1 = __builtin_amdgcn_mfma_f32_16x16x32_bf16(A3, eB[3][1], ac1, 0, 0, 0);\
    const int nA[4] = {nr.x, nr.y, nr.z, nr.w};                               \
    int nnw[4];                                                               \
    _Pragma("unroll") for (int r_ = 0; r_ < 4; ++r_) {                        \
      float y0 = ac0[r_] * xv[2 * r_];                                        \
      float y1 = ac1[r_] * xv[2 * r_ + 1];                                    \
      float v0 = ldexpf(y0, -nA[r_]);                                         \
      float v1 = ldexpf(y1, -nA[r_]);                                         \
      if ((T_) < lenr[r_]) {                                                  \
        unsigned pk = (unsigned)f2bf(v0) | ((unsigned)f2bf(v1) << 16);        \
        *(unsigned*)&sV[POUT][(4 * qd + r_) * STH + 32 * w + 2 * c] = pk;     \
        cloc[r_] += nA[r_];                                                   \
      }                                                                       \
      nnw[r_] = ((int)((__float_as_uint(v0) >> 23) & 0xFF)) - 120;            \
    }                                                                         \
    if (nwriter)                                                              \
      *(int4*)&nrm[POUT][4 * qd] = make_int4(nnw[0], nnw[1], nnw[2], nnw[3]); \
    _Pragma("unroll") for (int i_ = 0; i_ < 8; ++i_)                          \
        xv[i_] = __expf(RO[i_]);                                              \
    __syncthreads();                                                          \
  } while (0)

  for (int t = 1; t < Lmax; t += 2) {
    CRF_STEP(t, 0, 1, ra, rb);
    if (t + 1 < Lmax) {
      CRF_STEP(t + 1, 1, 0, rb, ra);
    }
  }
#undef CRF_STEP

  if (nwriter) *(int4*)&sC[4 * qd] = make_int4(cloc[0], cloc[1], cloc[2], cloc[3]);
  __syncthreads();
  {
    const int m = tid >> 4, i16 = tid & 15;
    const int pb = (slen[m] - 1) & 1;
    float s = 0.f;
#pragma unroll
    for (int pp = 0; pp < 8; ++pp) {
      int p = i16 * 8 + pp;
      int j = orig_j(p);
      s += bf2f(sV[pb][m * STH + p]) * __expf(etrans[j]);
    }
    s += __shfl_xor(s, 1, 64);
    s += __shfl_xor(s, 2, 64);
    s += __shfl_xor(s, 4, 64);
    s += __shfl_xor(s, 8, 64);
    if (i16 == 0)
      atomicAdd(&ws[0], (float)sC[m] * 0.69314718f + __logf(s));
  }
  __syncthreads();
  if (tid == 0) {
    __threadfence();
    unsigned old = atomicAdd((unsigned*)ws + 3, 1u);
    if (old == NWG - 1) {
      float zz = atomicAdd(&ws[0], 0.f);
      float ss = atomicAdd(&ws[1], 0.f);
      out[0] = (zz - ss) * (1.0f / (float)BB);
    }
  }
}

extern "C" void kernel_launch(void* const* d_in, const int* in_sizes, int n_in,
                              void* d_out, int out_size, void* d_ws, size_t ws_size,
                              hipStream_t stream) {
  const float* emit = (const float*)d_in[0];
  const int* target = (const int*)d_in[1];
  const void* mask = (const void*)d_in[2];
  const float* trans = (const float*)d_in[3];
  const float* strans = (const float*)d_in[4];
  const float* etrans = (const float*)d_in[5];
  float* ws = (float*)d_ws;
  float* out = (float*)d_out;

  const size_t need = (size_t)XQ_OFF + XQ_SZ;
  hipMemsetAsync(d_ws, 0, 16, stream);
  if (ws_size >= need) {
    int* lens = (int*)((char*)d_ws + LENS_OFF);
    float* AF = (float*)((char*)d_ws + AF_OFF);
    int* CF = (int*)((char*)d_ws + CF_OFF);
    float* BU = (float*)((char*)d_ws + BU_OFF);
    int* CB = (int*)((char*)d_ws + CB_OFF);
    uint4* Xq = (uint4*)((char*)d_ws + XQ_OFF);
    crf_expemit<<<NWG * TT, 256, 0, stream>>>(emit, Xq);
    crf_score_k<<<TT, BB, 0, stream>>>(emit, target, mask, trans, strans,
                                       etrans, ws, lens);
    crf_fb<<<2 * NWG, 256, 0, stream>>>(emit, trans, strans, etrans,
                                        (const uint4*)Xq, lens, AF, CF, BU, CB);
    crf_comb<<<NWG, 256, 0, stream>>>(trans, etrans, lens, AF, CF, BU, CB, ws,
                                      out);
  } else {
    crf_fused_fb<<<NWG, 256, 0, stream>>>(emit, target, mask, trans, strans,
                                          etrans, ws, out);
  }
}